// Round 6
// baseline (1236.170 us; speedup 1.0000x reference)
//
#include <hip/hip_runtime.h>
#include <math.h>

#define B_ 8
#define N_ 2048
#define DIM 512
#define HEADS 8
#define DHEAD 64
#define TOKENS (B_ * N_)                 // 16384
#define SZ ((size_t)TOKENS * DIM)        // 8388608 elements per [B,H,N,64] set
#define SCALE_ 8.0f
#define EPS_ 1e-12f
#define SQRT_DIM 22.62741699796952f      // sqrt(512)
#define MB16 ((size_t)16 * 1024 * 1024)

typedef unsigned long long u64;
typedef __attribute__((ext_vector_type(8))) short s8v;     // 8 bf16 (4 VGPR)
typedef __attribute__((ext_vector_type(16))) float f16v;   // MFMA 32x32 acc

#define MFMA(a, b, c) __builtin_amdgcn_mfma_f32_32x32x16_bf16(a, b, c, 0, 0, 0)

__device__ __forceinline__ ushort f2bf(float f) {
    uint u = __float_as_uint(f);
    return (ushort)((u + 0x7FFFu + ((u >> 16) & 1u)) >> 16);
}
__device__ __forceinline__ float bf2f(ushort h) {
    return __uint_as_float(((uint)h) << 16);
}
__device__ __forceinline__ void split2(float x, ushort& h, ushort& l) {
    h = f2bf(x);
    l = f2bf(x - bf2f(h));
}

union BF8 { u64 q[2]; ushort us[8]; s8v v; };

// attn LDS swizzle, 8-ushort granular: keeps 16B groups contiguous so every
// fragment read/write is one ds_read/write_b128; banks spread conflict-free.
__device__ __forceinline__ int swz8(int row, int col) {
    return row * 64 + (col ^ ((row & 7) << 3));
}

// ---------------------------------------------------------------------------
// K0: transpose + split  W[K][N] f32  ->  WT_hi / WT_lo [N][K] bf16 planes.
// ---------------------------------------------------------------------------
__global__ __launch_bounds__(256) void split_w_k(const float* __restrict__ W,
                                                 ushort* __restrict__ WThi,
                                                 ushort* __restrict__ WTlo,
                                                 int K, int N) {
    __shared__ float T[32][33];
    const int k0 = blockIdx.y * 32, n0 = blockIdx.x * 32;
    const int tr = threadIdx.x >> 5;
    const int tc = threadIdx.x & 31;
#pragma unroll
    for (int i = 0; i < 4; ++i)
        T[tr + 8 * i][tc] = W[(size_t)(k0 + tr + 8 * i) * N + n0 + tc];
    __syncthreads();
#pragma unroll
    for (int i = 0; i < 4; ++i) {
        const int n = tr + 8 * i;
        ushort h, l;
        split2(T[tc][n], h, l);
        WThi[(size_t)(n0 + n) * K + k0 + tc] = h;
        WTlo[(size_t)(n0 + n) * K + k0 + tc] = l;
    }
}

// ---------------------------------------------------------------------------
// K1: RMSNorm -> hi/lo bf16 planes [token][512].
// ---------------------------------------------------------------------------
__global__ __launch_bounds__(256) void rmsnorm_k(const float* __restrict__ x,
                                                 const float* __restrict__ g,
                                                 ushort* __restrict__ xnhi,
                                                 ushort* __restrict__ xnlo) {
    const int wave = threadIdx.x >> 6;
    const int lane = threadIdx.x & 63;
    const size_t t = (size_t)blockIdx.x * 4 + wave;
    const float4* xp = (const float4*)(x + t * DIM + lane * 8);
    float4 v0 = xp[0], v1 = xp[1];
    float ss = v0.x * v0.x + v0.y * v0.y + v0.z * v0.z + v0.w * v0.w +
               v1.x * v1.x + v1.y * v1.y + v1.z * v1.z + v1.w * v1.w;
#pragma unroll
    for (int off = 32; off; off >>= 1) ss += __shfl_xor(ss, off);
    const float s = SQRT_DIM / fmaxf(sqrtf(ss), EPS_);
    const float4* gp = (const float4*)(g + lane * 8);
    float4 g0 = gp[0], g1 = gp[1];
    float ov[8] = {v0.x * s * g0.x, v0.y * s * g0.y, v0.z * s * g0.z,
                   v0.w * s * g0.w, v1.x * s * g1.x, v1.y * s * g1.y,
                   v1.z * s * g1.z, v1.w * s * g1.w};
    ushort h[8], l[8];
#pragma unroll
    for (int j = 0; j < 8; ++j) split2(ov[j], h[j], l[j]);
    uint4 H, L;
    H.x = (uint)h[0] | ((uint)h[1] << 16); H.y = (uint)h[2] | ((uint)h[3] << 16);
    H.z = (uint)h[4] | ((uint)h[5] << 16); H.w = (uint)h[6] | ((uint)h[7] << 16);
    L.x = (uint)l[0] | ((uint)l[1] << 16); L.y = (uint)l[2] | ((uint)l[3] << 16);
    L.z = (uint)l[4] | ((uint)l[5] << 16); L.w = (uint)l[6] | ((uint)l[7] << 16);
    *(uint4*)(xnhi + t * DIM + lane * 8) = H;
    *(uint4*)(xnlo + t * DIM + lane * 8) = L;
}

// ---------------------------------------------------------------------------
// K2: QKV GEMM (split-bf16 MFMA) + FUSED epilogue:
//   q,k: per-head l2norm (5x shfl_xor within 32-lane half), *scale
//        (q also *8 softmax scale), split -> q/k hi/lo planes [B,H,N,64].
//   v:   split -> TRANSPOSED planes [B,H,64,N] (attn B-frag layout).
// Tile 128x128, BK=32, 4 waves (2x2).
// ---------------------------------------------------------------------------
__global__ __launch_bounds__(256, 2) void qkv_gemm_k(
    const ushort* __restrict__ Ahi, const ushort* __restrict__ Alo,
    const ushort* __restrict__ Bhi, const ushort* __restrict__ Blo,
    const float* __restrict__ q_scale, const float* __restrict__ k_scale,
    ushort* __restrict__ qhi, ushort* __restrict__ qlo,
    ushort* __restrict__ khi, ushort* __restrict__ klo,
    ushort* __restrict__ vthi, ushort* __restrict__ vtlo) {
    __shared__ __attribute__((aligned(16))) ushort Ah[128 * 36];
    __shared__ __attribute__((aligned(16))) ushort Al[128 * 36];
    __shared__ __attribute__((aligned(16))) ushort Bh[128 * 36];
    __shared__ __attribute__((aligned(16))) ushort Bl[128 * 36];
    const int row0 = blockIdx.y * 128;
    const int col0 = blockIdx.x * 128;
    const int tid = threadIdx.x;
    const int wv = tid >> 6;
    const int wy = wv >> 1, wx = wv & 1;
    const int lo5 = tid & 31;
    const int hi5 = (tid & 63) >> 5;
    const int sr = tid >> 1;
    const int sh = (tid & 1) * 16;

    f16v acc[2][2];
#pragma unroll
    for (int i = 0; i < 2; ++i)
#pragma unroll
        for (int j = 0; j < 2; ++j)
#pragma unroll
            for (int r = 0; r < 16; ++r) acc[i][j][r] = 0.0f;

    uint4 ra[2][2], rb[2][2];
    const size_t abase = (size_t)(row0 + sr) * DIM + sh;
    const size_t bbase = (size_t)(col0 + sr) * DIM + sh;
    ra[0][0] = *(const uint4*)(Ahi + abase);  ra[0][1] = *(const uint4*)(Ahi + abase + 8);
    ra[1][0] = *(const uint4*)(Alo + abase);  ra[1][1] = *(const uint4*)(Alo + abase + 8);
    rb[0][0] = *(const uint4*)(Bhi + bbase);  rb[0][1] = *(const uint4*)(Bhi + bbase + 8);
    rb[1][0] = *(const uint4*)(Blo + bbase);  rb[1][1] = *(const uint4*)(Blo + bbase + 8);

    const int sbase = sr * 36 + sh;
    for (int k0 = 0; k0 < DIM; k0 += 32) {
        __syncthreads();
        *(uint4*)&Ah[sbase] = ra[0][0]; *(uint4*)&Ah[sbase + 8] = ra[0][1];
        *(uint4*)&Al[sbase] = ra[1][0]; *(uint4*)&Al[sbase + 8] = ra[1][1];
        *(uint4*)&Bh[sbase] = rb[0][0]; *(uint4*)&Bh[sbase + 8] = rb[0][1];
        *(uint4*)&Bl[sbase] = rb[1][0]; *(uint4*)&Bl[sbase + 8] = rb[1][1];
        __syncthreads();
        if (k0 + 32 < DIM) {
            const size_t a2 = abase + k0 + 32, b2 = bbase + k0 + 32;
            ra[0][0] = *(const uint4*)(Ahi + a2); ra[0][1] = *(const uint4*)(Ahi + a2 + 8);
            ra[1][0] = *(const uint4*)(Alo + a2); ra[1][1] = *(const uint4*)(Alo + a2 + 8);
            rb[0][0] = *(const uint4*)(Bhi + b2); rb[0][1] = *(const uint4*)(Bhi + b2 + 8);
            rb[1][0] = *(const uint4*)(Blo + b2); rb[1][1] = *(const uint4*)(Blo + b2 + 8);
        }
#pragma unroll
        for (int ks = 0; ks < 2; ++ks) {
            s8v a_h[2], a_l[2], b_h[2], b_l[2];
#pragma unroll
            for (int rt = 0; rt < 2; ++rt) {
                const int off = (wy * 64 + rt * 32 + lo5) * 36 + ks * 16 + 8 * hi5;
                BF8 th, tl;
                th.q[0] = *(const u64*)&Ah[off]; th.q[1] = *(const u64*)&Ah[off + 4];
                tl.q[0] = *(const u64*)&Al[off]; tl.q[1] = *(const u64*)&Al[off + 4];
                a_h[rt] = th.v; a_l[rt] = tl.v;
            }
#pragma unroll
            for (int ct = 0; ct < 2; ++ct) {
                const int off = (wx * 64 + ct * 32 + lo5) * 36 + ks * 16 + 8 * hi5;
                BF8 th, tl;
                th.q[0] = *(const u64*)&Bh[off]; th.q[1] = *(const u64*)&Bh[off + 4];
                tl.q[0] = *(const u64*)&Bl[off]; tl.q[1] = *(const u64*)&Bl[off + 4];
                b_h[ct] = th.v; b_l[ct] = tl.v;
            }
#pragma unroll
            for (int rt = 0; rt < 2; ++rt)
#pragma unroll
                for (int ct = 0; ct < 2; ++ct) {
                    acc[rt][ct] = MFMA(a_h[rt], b_h[ct], acc[rt][ct]);
                    acc[rt][ct] = MFMA(a_l[rt], b_h[ct], acc[rt][ct]);
                    acc[rt][ct] = MFMA(a_h[rt], b_l[ct], acc[rt][ct]);
                }
        }
    }
    // ---- fused epilogue ----
    const int c64 = col0 + wx * 64;       // wave col base (64-aligned)
    const int which = c64 >> 9;           // 0=q 1=k 2=v
    const int h = (c64 & 511) >> 6;       // head (uniform per wave)
    if (which < 2) {
        const float* sc = which ? k_scale : q_scale;
        const float s0c = sc[lo5], s1c = sc[32 + lo5];
        ushort* Dh = which ? khi : qhi;
        ushort* Dl = which ? klo : qlo;
        const float mul = which ? 1.0f : SCALE_;   // fold softmax x8 into q
#pragma unroll
        for (int rt = 0; rt < 2; ++rt)
#pragma unroll
            for (int r = 0; r < 16; ++r) {
                float v0 = acc[rt][0][r], v1 = acc[rt][1][r];
                float ss = v0 * v0 + v1 * v1;
#pragma unroll
                for (int off = 16; off; off >>= 1) ss += __shfl_xor(ss, off);
                const float inv = mul / fmaxf(sqrtf(ss), EPS_);
                v0 *= inv * s0c; v1 *= inv * s1c;
                const int m = row0 + wy * 64 + rt * 32 + (r & 3) + 8 * (r >> 2) + 4 * hi5;
                const int b = m >> 11, n = m & 2047;
                const size_t rb_ = (((size_t)b * HEADS + h) * N_ + n) * DHEAD;
                ushort hh, ll;
                split2(v0, hh, ll); Dh[rb_ + lo5] = hh;      Dl[rb_ + lo5] = ll;
                split2(v1, hh, ll); Dh[rb_ + 32 + lo5] = hh; Dl[rb_ + 32 + lo5] = ll;
            }
    } else {
#pragma unroll
        for (int rt = 0; rt < 2; ++rt)
#pragma unroll
            for (int r = 0; r < 16; ++r) {
                const int m = row0 + wy * 64 + rt * 32 + (r & 3) + 8 * (r >> 2) + 4 * hi5;
                const int b = m >> 11, n = m & 2047;
                const size_t vbase = ((size_t)b * HEADS + h) * (DHEAD * (size_t)N_) + n;
                ushort hh, ll;
                split2(acc[rt][0][r], hh, ll);
                vthi[vbase + (size_t)lo5 * N_] = hh;
                vtlo[vbase + (size_t)lo5 * N_] = ll;
                split2(acc[rt][1][r], hh, ll);
                vthi[vbase + (size_t)(32 + lo5) * N_] = hh;
                vtlo[vbase + (size_t)(32 + lo5) * N_] = ll;
            }
    }
}

// ---------------------------------------------------------------------------
// K4: MFMA attention.  QBLK=128 (4 waves x 32q), KVBLK=64.
// All inputs pre-split bf16 hi/lo planes; staging = pure b128 copies.
// QK^T 3-term split; P single bf16 plane (denom from rounded P); PV pah x
// {vhi,vlo}.  swz8 swizzle -> every LDS access is b128, conflict-free.
// ---------------------------------------------------------------------------
__global__ __launch_bounds__(256, 3) void attn_k(
    const ushort* __restrict__ qhi, const ushort* __restrict__ qlo,
    const ushort* __restrict__ khi, const ushort* __restrict__ klo,
    const ushort* __restrict__ vthi, const ushort* __restrict__ vtlo,
    ushort* __restrict__ Ohi, ushort* __restrict__ Olo) {
    __shared__ __attribute__((aligned(16))) ushort Kh[64 * 64];
    __shared__ __attribute__((aligned(16))) ushort Kl[64 * 64];
    __shared__ __attribute__((aligned(16))) ushort Vh[64 * 64];
    __shared__ __attribute__((aligned(16))) ushort Vl[64 * 64];
    __shared__ __attribute__((aligned(16))) ushort Pbuf[4][32 * 64];

    const int bh = blockIdx.y;
    const int q0 = blockIdx.x * 128;
    const int tid = threadIdx.x;
    const int ws = tid >> 6;
    const int lo5 = tid & 31;
    const int hi5 = (tid & 63) >> 5;
    const size_t base = (size_t)bh * (N_ * DHEAD);
    const ushort* khp = khi + base;
    const ushort* klp = klo + base;
    const ushort* vhp = vthi + base;   // [d][n] rows of N_
    const ushort* vlp = vtlo + base;
    const int srow = tid >> 2;         // staging row 0..63
    const int scc = (tid & 3) * 16;    // staging col chunk

    // ---- Q fragments (pre-scaled, pre-split) ----
    const int qrow0 = q0 + ws * 32;
    const size_t qbase = base + (size_t)(qrow0 + lo5) * DHEAD;
    s8v qh[4], ql[4];
#pragma unroll
    for (int s = 0; s < 4; ++s) {
        const int d0 = 16 * s + 8 * hi5;
        qh[s] = *(const s8v*)(qhi + qbase + d0);
        ql[s] = *(const s8v*)(qlo + qbase + d0);
    }

    f16v o0 = {0,0,0,0,0,0,0,0,0,0,0,0,0,0,0,0};
    f16v o1 = {0,0,0,0,0,0,0,0,0,0,0,0,0,0,0,0};
    float dsum[16];
#pragma unroll
    for (int r = 0; r < 16; ++r) dsum[r] = 0.0f;
    ushort* Pw = Pbuf[ws];

    uint4 pre[8];
#define LDTILE(kt_)                                                            \
    {                                                                          \
        const size_t kr = (size_t)((kt_) * 64 + srow) * 64 + scc;              \
        pre[0] = *(const uint4*)(khp + kr); pre[1] = *(const uint4*)(khp + kr + 8); \
        pre[2] = *(const uint4*)(klp + kr); pre[3] = *(const uint4*)(klp + kr + 8); \
        const size_t vr = (size_t)srow * N_ + (kt_) * 64 + scc;                \
        pre[4] = *(const uint4*)(vhp + vr); pre[5] = *(const uint4*)(vhp + vr + 8); \
        pre[6] = *(const uint4*)(vlp + vr); pre[7] = *(const uint4*)(vlp + vr + 8); \
    }

    LDTILE(0)
    const int sb0 = swz8(srow, scc), sb1 = swz8(srow, scc + 8);
    for (int kt = 0; kt < N_ / 64; ++kt) {
        __syncthreads();
        *(uint4*)&Kh[sb0] = pre[0]; *(uint4*)&Kh[sb1] = pre[1];
        *(uint4*)&Kl[sb0] = pre[2]; *(uint4*)&Kl[sb1] = pre[3];
        *(uint4*)&Vh[sb0] = pre[4]; *(uint4*)&Vh[sb1] = pre[5];
        *(uint4*)&Vl[sb0] = pre[6]; *(uint4*)&Vl[sb1] = pre[7];
        __syncthreads();
        if (kt + 1 < N_ / 64) LDTILE(kt + 1)
        // ---- S = QK^T, 3-term split ----
        f16v s0 = {0,0,0,0,0,0,0,0,0,0,0,0,0,0,0,0};
        f16v s1 = {0,0,0,0,0,0,0,0,0,0,0,0,0,0,0,0};
#pragma unroll
        for (int s = 0; s < 4; ++s) {
            const int d0 = 16 * s + 8 * hi5;
            const s8v b0h = *(const s8v*)&Kh[swz8(lo5, d0)];
            const s8v b0l = *(const s8v*)&Kl[swz8(lo5, d0)];
            const s8v b1h = *(const s8v*)&Kh[swz8(32 + lo5, d0)];
            const s8v b1l = *(const s8v*)&Kl[swz8(32 + lo5, d0)];
            s0 = MFMA(qh[s], b0h, s0);
            s1 = MFMA(qh[s], b1h, s1);
            s0 = MFMA(ql[s], b0h, s0);
            s1 = MFMA(ql[s], b1h, s1);
            s0 = MFMA(qh[s], b0l, s0);
            s1 = MFMA(qh[s], b1l, s1);
        }
        // ---- P = bf16(exp(min(S,50))); denom from rounded P ----
#pragma unroll
        for (int r = 0; r < 16; ++r) {
            const float p0 = __expf(fminf(s0[r], 50.0f));
            const float p1 = __expf(fminf(s1[r], 50.0f));
            const ushort h0 = f2bf(p0);
            const ushort h1 = f2bf(p1);
            dsum[r] += bf2f(h0) + bf2f(h1);
            const int qr = (r & 3) + 8 * (r >> 2) + 4 * hi5;
            Pw[swz8(qr, lo5)] = h0;
            Pw[swz8(qr, 32 + lo5)] = h1;
        }
        // rule #18: drain per-wave P LDS writes; pin scheduler.
        asm volatile("s_waitcnt lgkmcnt(0)" ::: "memory");
        __builtin_amdgcn_sched_barrier(0);
        // ---- O += P V ----
#pragma unroll
        for (int s = 0; s < 4; ++s) {
            const int koff = 16 * s + 8 * hi5;
            BF8 pah;
            pah.q[0] = *(const u64*)&Pw[swz8(lo5, koff)];
            pah.q[1] = *(const u64*)&Pw[swz8(lo5, koff) + 4];
            const s8v v0h = *(const s8v*)&Vh[swz8(lo5, koff)];
            const s8v v0l = *(const s8v*)&Vl[swz8(lo5, koff)];
            const s8v v1h = *(const s8v*)&Vh[swz8(32 + lo5, koff)];
            const s8v v1l = *(const s8v*)&Vl[swz8(32 + lo5, koff)];
            o0 = MFMA(pah.v, v0h, o0);
            o1 = MFMA(pah.v, v1h, o1);
            o0 = MFMA(pah.v, v0l, o0);
            o1 = MFMA(pah.v, v1l, o1);
        }
    }
#pragma unroll
    for (int r = 0; r < 16; ++r) {
#pragma unroll
        for (int off = 1; off < 32; off <<= 1)
            dsum[r] += __shfl_xor(dsum[r], off);
    }
    const int b = bh >> 3, hh = bh & 7;
#pragma unroll
    for (int r = 0; r < 16; ++r) {
        const int qr = (r & 3) + 8 * (r >> 2) + 4 * hi5;
        const float inv = 1.0f / dsum[r];
        const size_t rowb = ((size_t)b * N_ + qrow0 + qr) * DIM + hh * DHEAD;
        ushort h, l;
        split2(o0[r] * inv, h, l);
        Ohi[rowb + lo5] = h;      Olo[rowb + lo5] = l;
        split2(o1[r] * inv, h, l);
        Ohi[rowb + 32 + lo5] = h; Olo[rowb + 32 + lo5] = l;
    }
}

// ---------------------------------------------------------------------------
// K5: out GEMM (split-bf16 MFMA), plain f32 store.
// ---------------------------------------------------------------------------
__global__ __launch_bounds__(256, 2) void out_gemm_k(
    const ushort* __restrict__ Ahi, const ushort* __restrict__ Alo,
    const ushort* __restrict__ Bhi, const ushort* __restrict__ Blo,
    float* __restrict__ out) {
    __shared__ __attribute__((aligned(16))) ushort Ah[128 * 36];
    __shared__ __attribute__((aligned(16))) ushort Al[128 * 36];
    __shared__ __attribute__((aligned(16))) ushort Bh[128 * 36];
    __shared__ __attribute__((aligned(16))) ushort Bl[128 * 36];
    const int row0 = blockIdx.y * 128;
    const int col0 = blockIdx.x * 128;
    const int tid = threadIdx.x;
    const int wv = tid >> 6;
    const int wy = wv >> 1, wx = wv & 1;
    const int lo5 = tid & 31;
    const int hi5 = (tid & 63) >> 5;
    const int sr = tid >> 1;
    const int sh = (tid & 1) * 16;

    f16v acc[2][2];
#pragma unroll
    for (int i = 0; i < 2; ++i)
#pragma unroll
        for (int j = 0; j < 2; ++j)
#pragma unroll
            for (int r = 0; r < 16; ++r) acc[i][j][r] = 0.0f;

    uint4 ra[2][2], rb[2][2];
    const size_t abase = (size_t)(row0 + sr) * DIM + sh;
    const size_t bbase = (size_t)(col0 + sr) * DIM + sh;
    ra[0][0] = *(const uint4*)(Ahi + abase);  ra[0][1] = *(const uint4*)(Ahi + abase + 8);
    ra[1][0] = *(const uint4*)(Alo + abase);  ra[1][1] = *(const uint4*)(Alo + abase + 8);
    rb[0][0] = *(const uint4*)(Bhi + bbase);  rb[0][1] = *(const uint4*)(Bhi + bbase + 8);
    rb[1][0] = *(const uint4*)(Blo + bbase);  rb[1][1] = *(const uint4*)(Blo + bbase + 8);

    const int sbase = sr * 36 + sh;
    for (int k0 = 0; k0 < DIM; k0 += 32) {
        __syncthreads();
        *(uint4*)&Ah[sbase] = ra[0][0]; *(uint4*)&Ah[sbase + 8] = ra[0][1];
        *(uint4*)&Al[sbase] = ra[1][0]; *(uint4*)&Al[sbase + 8] = ra[1][1];
        *(uint4*)&Bh[sbase] = rb[0][0]; *(uint4*)&Bh[sbase + 8] = rb[0][1];
        *(uint4*)&Bl[sbase] = rb[1][0]; *(uint4*)&Bl[sbase + 8] = rb[1][1];
        __syncthreads();
        if (k0 + 32 < DIM) {
            const size_t a2 = abase + k0 + 32, b2 = bbase + k0 + 32;
            ra[0][0] = *(const uint4*)(Ahi + a2); ra[0][1] = *(const uint4*)(Ahi + a2 + 8);
            ra[1][0] = *(const uint4*)(Alo + a2); ra[1][1] = *(const uint4*)(Alo + a2 + 8);
            rb[0][0] = *(const uint4*)(Bhi + b2); rb[0][1] = *(const uint4*)(Bhi + b2 + 8);
            rb[1][0] = *(const uint4*)(Blo + b2); rb[1][1] = *(const uint4*)(Blo + b2 + 8);
        }
#pragma unroll
        for (int ks = 0; ks < 2; ++ks) {
            s8v a_h[2], a_l[2], b_h[2], b_l[2];
#pragma unroll
            for (int rt = 0; rt < 2; ++rt) {
                const int off = (wy * 64 + rt * 32 + lo5) * 36 + ks * 16 + 8 * hi5;
                BF8 th, tl;
                th.q[0] = *(const u64*)&Ah[off]; th.q[1] = *(const u64*)&Ah[off + 4];
                tl.q[0] = *(const u64*)&Al[off]; tl.q[1] = *(const u64*)&Al[off + 4];
                a_h[rt] = th.v; a_l[rt] = tl.v;
            }
#pragma unroll
            for (int ct = 0; ct < 2; ++ct) {
                const int off = (wx * 64 + ct * 32 + lo5) * 36 + ks * 16 + 8 * hi5;
                BF8 th, tl;
                th.q[0] = *(const u64*)&Bh[off]; th.q[1] = *(const u64*)&Bh[off + 4];
                tl.q[0] = *(const u64*)&Bl[off]; tl.q[1] = *(const u64*)&Bl[off + 4];
                b_h[ct] = th.v; b_l[ct] = tl.v;
            }
#pragma unroll
            for (int rt = 0; rt < 2; ++rt)
#pragma unroll
                for (int ct = 0; ct < 2; ++ct) {
                    acc[rt][ct] = MFMA(a_h[rt], b_h[ct], acc[rt][ct]);
                    acc[rt][ct] = MFMA(a_l[rt], b_h[ct], acc[rt][ct]);
                    acc[rt][ct] = MFMA(a_h[rt], b_l[ct], acc[rt][ct]);
                }
        }
    }
#pragma unroll
    for (int rt = 0; rt < 2; ++rt)
#pragma unroll
        for (int ct = 0; ct < 2; ++ct) {
            const int c = col0 + wx * 64 + ct * 32 + lo5;
#pragma unroll
            for (int r = 0; r < 16; ++r) {
                const int m = row0 + wy * 64 + rt * 32 + (r & 3) + 8 * (r >> 2) + 4 * hi5;
                out[(size_t)m * DIM + c] = acc[rt][ct][r];
            }
        }
}

// ---------------------------------------------------------------------------
extern "C" void kernel_launch(void* const* d_in, const int* in_sizes, int n_in,
                              void* d_out, int out_size, void* d_ws, size_t ws_size,
                              hipStream_t stream) {
    const float* x       = (const float*)d_in[0];
    const float* g       = (const float*)d_in[1];
    const float* w_qkv   = (const float*)d_in[2];
    const float* q_scale = (const float*)d_in[3];
    const float* k_scale = (const float*)d_in[4];
    const float* w_out   = (const float*)d_in[5];
    float* out = (float*)d_out;

    if (ws_size < 8 * MB16) return;   // need 128 MiB scratch

    char* W = (char*)d_ws;
    ushort* xnhi = (ushort*)W;                  // 16MB
    ushort* xnlo = (ushort*)(W + MB16);         // 16MB
    ushort* qhi  = (ushort*)(W + 2 * MB16);
    ushort* qlo  = (ushort*)(W + 3 * MB16);
    ushort* khi  = (ushort*)(W + 4 * MB16);
    ushort* klo  = (ushort*)(W + 5 * MB16);
    ushort* vthi = (ushort*)(W + 6 * MB16);
    ushort* vtlo = (ushort*)(W + 7 * MB16);
    ushort* Ohi  = xnhi;                        // reuse (xn dead after gemm0)
    ushort* Olo  = xnlo;
    // w_qkv^T planes in d_out (scratch until out_gemm overwrites it)
    ushort* wqh = (ushort*)d_out;
    ushort* wql = wqh + (size_t)1536 * 512;
    // w_out^T planes in qhi region (q dead after attn; split runs after attn)
    ushort* woh = qhi;
    ushort* wol = qhi + (size_t)512 * 512;

    split_w_k<<<dim3(48, 16), 256, 0, stream>>>(w_qkv, wqh, wql, 512, 1536);
    rmsnorm_k<<<TOKENS / 4, 256, 0, stream>>>(x, g, xnhi, xnlo);
    qkv_gemm_k<<<dim3(12, TOKENS / 128), 256, 0, stream>>>(
        xnhi, xnlo, wqh, wql, q_scale, k_scale,
        qhi, qlo, khi, klo, vthi, vtlo);
    attn_k<<<dim3(N_ / 128, B_ * HEADS), 256, 0, stream>>>(
        qhi, qlo, khi, klo, vthi, vtlo, Ohi, Olo);
    split_w_k<<<dim3(16, 16), 256, 0, stream>>>(w_out, woh, wol, 512, 512);
    out_gemm_k<<<dim3(4, TOKENS / 128), 256, 0, stream>>>(Ohi, Olo, woh, wol, out);
}

// Round 8
// 1090.717 us; speedup vs baseline: 1.1334x; 1.1334x over previous
//
#include <hip/hip_runtime.h>
#include <math.h>

#define B_ 8
#define N_ 2048
#define DIM 512
#define HEADS 8
#define DHEAD 64
#define TOKENS (B_ * N_)                 // 16384
#define SCALE_ 8.0f
#define EPS_ 1e-12f
#define SQRT_DIM 22.62741699796952f      // sqrt(512)
#define MB16 ((size_t)16 * 1024 * 1024)

typedef unsigned long long u64;
typedef __attribute__((ext_vector_type(8))) short s8v;     // 8 bf16 (4 VGPR)
typedef __attribute__((ext_vector_type(16))) float f16v;   // MFMA 32x32 acc

#define MFMA(a, b, c) __builtin_amdgcn_mfma_f32_32x32x16_bf16(a, b, c, 0, 0, 0)

__device__ __forceinline__ ushort f2bf(float f) {
    uint u = __float_as_uint(f);
    return (ushort)((u + 0x7FFFu + ((u >> 16) & 1u)) >> 16);
}
__device__ __forceinline__ float bf2f(ushort h) {
    return __uint_as_float(((uint)h) << 16);
}
__device__ __forceinline__ void split2(float x, ushort& h, ushort& l) {
    h = f2bf(x);
    l = f2bf(x - bf2f(h));
}

union BF8 { u64 q[2]; ushort us[8]; s8v v; };

// attn LDS swizzle, 8-ushort granular: every access stays one b128 op.
__device__ __forceinline__ int swz8(int row, int col) {
    return row * 64 + (col ^ ((row & 7) << 3));
}

// ---------------------------------------------------------------------------
// K0: transpose + split  W[K][N] f32  ->  WT_hi / WT_lo [N][K] bf16 planes.
// ---------------------------------------------------------------------------
__global__ __launch_bounds__(256) void split_w_k(const float* __restrict__ W,
                                                 ushort* __restrict__ WThi,
                                                 ushort* __restrict__ WTlo,
                                                 int K, int N) {
    __shared__ float T[32][33];
    const int k0 = blockIdx.y * 32, n0 = blockIdx.x * 32;
    const int tr = threadIdx.x >> 5;
    const int tc = threadIdx.x & 31;
#pragma unroll
    for (int i = 0; i < 4; ++i)
        T[tr + 8 * i][tc] = W[(size_t)(k0 + tr + 8 * i) * N + n0 + tc];
    __syncthreads();
#pragma unroll
    for (int i = 0; i < 4; ++i) {
        const int n = tr + 8 * i;
        ushort h, l;
        split2(T[tc][n], h, l);
        WThi[(size_t)(n0 + n) * K + k0 + tc] = h;
        WTlo[(size_t)(n0 + n) * K + k0 + tc] = l;
    }
}

// ---------------------------------------------------------------------------
// K1: RMSNorm -> hi/lo bf16 planes [token][512].
// ---------------------------------------------------------------------------
__global__ __launch_bounds__(256) void rmsnorm_k(const float* __restrict__ x,
                                                 const float* __restrict__ g,
                                                 ushort* __restrict__ xnhi,
                                                 ushort* __restrict__ xnlo) {
    const int wave = threadIdx.x >> 6;
    const int lane = threadIdx.x & 63;
    const size_t t = (size_t)blockIdx.x * 4 + wave;
    const float4* xp = (const float4*)(x + t * DIM + lane * 8);
    float4 v0 = xp[0], v1 = xp[1];
    float ss = v0.x * v0.x + v0.y * v0.y + v0.z * v0.z + v0.w * v0.w +
               v1.x * v1.x + v1.y * v1.y + v1.z * v1.z + v1.w * v1.w;
#pragma unroll
    for (int off = 32; off; off >>= 1) ss += __shfl_xor(ss, off);
    const float s = SQRT_DIM / fmaxf(sqrtf(ss), EPS_);
    const float4* gp = (const float4*)(g + lane * 8);
    float4 g0 = gp[0], g1 = gp[1];
    float ov[8] = {v0.x * s * g0.x, v0.y * s * g0.y, v0.z * s * g0.z,
                   v0.w * s * g0.w, v1.x * s * g1.x, v1.y * s * g1.y,
                   v1.z * s * g1.z, v1.w * s * g1.w};
    ushort h[8], l[8];
#pragma unroll
    for (int j = 0; j < 8; ++j) split2(ov[j], h[j], l[j]);
    uint4 H, L;
    H.x = (uint)h[0] | ((uint)h[1] << 16); H.y = (uint)h[2] | ((uint)h[3] << 16);
    H.z = (uint)h[4] | ((uint)h[5] << 16); H.w = (uint)h[6] | ((uint)h[7] << 16);
    L.x = (uint)l[0] | ((uint)l[1] << 16); L.y = (uint)l[2] | ((uint)l[3] << 16);
    L.z = (uint)l[4] | ((uint)l[5] << 16); L.w = (uint)l[6] | ((uint)l[7] << 16);
    *(uint4*)(xnhi + t * DIM + lane * 8) = H;
    *(uint4*)(xnlo + t * DIM + lane * 8) = L;
}

// ---------------------------------------------------------------------------
// K2: QKV GEMM (split-bf16 MFMA) + fused epilogue.
//   q,k: per-head l2norm + scale (+x8 into q), split -> [B,H,N,64] planes.
//   v:   LDS-transposed -> coalesced [B,H,64,N] plane stores (128B segments).
// Grid: 1536 blocks 1D, XCD-swizzled.  Tile 128x128, BK=32, 4 waves.
// ---------------------------------------------------------------------------
__global__ __launch_bounds__(256, 2) void qkv_gemm_k(
    const ushort* __restrict__ Ahi, const ushort* __restrict__ Alo,
    const ushort* __restrict__ Bhi, const ushort* __restrict__ Blo,
    const float* __restrict__ q_scale, const float* __restrict__ k_scale,
    ushort* __restrict__ qhi, ushort* __restrict__ qlo,
    ushort* __restrict__ khi, ushort* __restrict__ klo,
    ushort* __restrict__ vthi, ushort* __restrict__ vtlo) {
    __shared__ __attribute__((aligned(16))) ushort pool[4 * 128 * 36];
    ushort* Ah = pool;
    ushort* Al = pool + 4608;
    ushort* Bh = pool + 9216;
    ushort* Bl = pool + 13824;

    const int hw = blockIdx.x;
    const int lg = (hw & 7) * 192 + (hw >> 3);     // XCD swizzle (1536 wgs)
    const int bx = lg % 12;
    const int by = lg / 12;
    const int row0 = by * 128;
    const int col0 = bx * 128;
    const int tid = threadIdx.x;
    const int lane = tid & 63;
    const int wv = tid >> 6;
    const int wy = wv >> 1, wx = wv & 1;
    const int lo5 = tid & 31;
    const int hi5 = (tid & 63) >> 5;
    const int sr = tid >> 1;
    const int sh = (tid & 1) * 16;

    f16v acc[2][2];
#pragma unroll
    for (int i = 0; i < 2; ++i)
#pragma unroll
        for (int j = 0; j < 2; ++j)
#pragma unroll
            for (int r = 0; r < 16; ++r) acc[i][j][r] = 0.0f;

    uint4 ra[2][2], rb[2][2];
    const size_t abase = (size_t)(row0 + sr) * DIM + sh;
    const size_t bbase = (size_t)(col0 + sr) * DIM + sh;
    ra[0][0] = *(const uint4*)(Ahi + abase);  ra[0][1] = *(const uint4*)(Ahi + abase + 8);
    ra[1][0] = *(const uint4*)(Alo + abase);  ra[1][1] = *(const uint4*)(Alo + abase + 8);
    rb[0][0] = *(const uint4*)(Bhi + bbase);  rb[0][1] = *(const uint4*)(Bhi + bbase + 8);
    rb[1][0] = *(const uint4*)(Blo + bbase);  rb[1][1] = *(const uint4*)(Blo + bbase + 8);

    const int sbase = sr * 36 + sh;
    for (int k0 = 0; k0 < DIM; k0 += 32) {
        __syncthreads();
        *(uint4*)&Ah[sbase] = ra[0][0]; *(uint4*)&Ah[sbase + 8] = ra[0][1];
        *(uint4*)&Al[sbase] = ra[1][0]; *(uint4*)&Al[sbase + 8] = ra[1][1];
        *(uint4*)&Bh[sbase] = rb[0][0]; *(uint4*)&Bh[sbase + 8] = rb[0][1];
        *(uint4*)&Bl[sbase] = rb[1][0]; *(uint4*)&Bl[sbase + 8] = rb[1][1];
        __syncthreads();
        if (k0 + 32 < DIM) {
            const size_t a2 = abase + k0 + 32, b2 = bbase + k0 + 32;
            ra[0][0] = *(const uint4*)(Ahi + a2); ra[0][1] = *(const uint4*)(Ahi + a2 + 8);
            ra[1][0] = *(const uint4*)(Alo + a2); ra[1][1] = *(const uint4*)(Alo + a2 + 8);
            rb[0][0] = *(const uint4*)(Bhi + b2); rb[0][1] = *(const uint4*)(Bhi + b2 + 8);
            rb[1][0] = *(const uint4*)(Blo + b2); rb[1][1] = *(const uint4*)(Blo + b2 + 8);
        }
#pragma unroll
        for (int ks = 0; ks < 2; ++ks) {
            s8v a_h[2], a_l[2], b_h[2], b_l[2];
#pragma unroll
            for (int rt = 0; rt < 2; ++rt) {
                const int off = (wy * 64 + rt * 32 + lo5) * 36 + ks * 16 + 8 * hi5;
                BF8 th, tl;
                th.q[0] = *(const u64*)&Ah[off]; th.q[1] = *(const u64*)&Ah[off + 4];
                tl.q[0] = *(const u64*)&Al[off]; tl.q[1] = *(const u64*)&Al[off + 4];
                a_h[rt] = th.v; a_l[rt] = tl.v;
            }
#pragma unroll
            for (int ct = 0; ct < 2; ++ct) {
                const int off = (wx * 64 + ct * 32 + lo5) * 36 + ks * 16 + 8 * hi5;
                BF8 th, tl;
                th.q[0] = *(const u64*)&Bh[off]; th.q[1] = *(const u64*)&Bh[off + 4];
                tl.q[0] = *(const u64*)&Bl[off]; tl.q[1] = *(const u64*)&Bl[off + 4];
                b_h[ct] = th.v; b_l[ct] = tl.v;
            }
#pragma unroll
            for (int rt = 0; rt < 2; ++rt)
#pragma unroll
                for (int ct = 0; ct < 2; ++ct) {
                    acc[rt][ct] = MFMA(a_h[rt], b_h[ct], acc[rt][ct]);
                    acc[rt][ct] = MFMA(a_l[rt], b_h[ct], acc[rt][ct]);
                    acc[rt][ct] = MFMA(a_h[rt], b_l[ct], acc[rt][ct]);
                }
        }
    }
    // ---- fused epilogue ----
    const int which = col0 >> 9;          // block-uniform: 0=q 1=k 2=v
    const int c64 = col0 + wx * 64;
    const int h = (c64 & 511) >> 6;       // head (uniform per wave)
    if (which < 2) {
        const float* sc = which ? k_scale : q_scale;
        const float s0c = sc[lo5], s1c = sc[32 + lo5];
        ushort* Dh = which ? khi : qhi;
        ushort* Dl = which ? klo : qlo;
        const float mul = which ? 1.0f : SCALE_;   // fold softmax x8 into q
#pragma unroll
        for (int rt = 0; rt < 2; ++rt)
#pragma unroll
            for (int r = 0; r < 16; ++r) {
                float v0 = acc[rt][0][r], v1 = acc[rt][1][r];
                float ss = v0 * v0 + v1 * v1;
#pragma unroll
                for (int off = 16; off; off >>= 1) ss += __shfl_xor(ss, off);
                const float inv = mul / fmaxf(sqrtf(ss), EPS_);
                v0 *= inv * s0c; v1 *= inv * s1c;
                const int m = row0 + wy * 64 + rt * 32 + (r & 3) + 8 * (r >> 2) + 4 * hi5;
                const int b = m >> 11, n = m & 2047;
                const size_t rb_ = (((size_t)b * HEADS + h) * N_ + n) * DHEAD;
                ushort hh, ll;
                split2(v0, hh, ll); Dh[rb_ + lo5] = hh;      Dl[rb_ + lo5] = ll;
                split2(v1, hh, ll); Dh[rb_ + 32 + lo5] = hh; Dl[rb_ + 32 + lo5] = ll;
            }
    } else {
        // V: per-wave LDS transpose (reuse staging pool) -> coalesced stores.
        __syncthreads();                       // staging pool now reusable
        ushort* tb = pool + wv * (64 * 72);    // [64 d][72 stride] ushorts
        const int bB = row0 >> 11;
        const int nbase = (row0 & 2047) + wy * 64;   // FIX: within-batch token
        const size_t vb0 = (((size_t)bB * HEADS + h) * DHEAD) * (size_t)N_;
#pragma unroll
        for (int plane = 0; plane < 2; ++plane) {
#pragma unroll
            for (int rt = 0; rt < 2; ++rt)
#pragma unroll
                for (int ct = 0; ct < 2; ++ct)
#pragma unroll
                    for (int r = 0; r < 16; ++r) {
                        ushort hh, ll;
                        split2(acc[rt][ct][r], hh, ll);
                        const int ml = rt * 32 + (r & 3) + 8 * (r >> 2) + 4 * hi5;
                        const int dl = ct * 32 + lo5;
                        tb[dl * 72 + ml] = plane ? ll : hh;
                    }
            asm volatile("s_waitcnt lgkmcnt(0)" ::: "memory");
            __builtin_amdgcn_sched_barrier(0);
            ushort* dst = plane ? vtlo : vthi;
#pragma unroll
            for (int i = 0; i < 8; ++i) {
                const int d = (lane >> 3) + 8 * i;
                const int ml = (lane & 7) * 8;
                uint4 w = *(const uint4*)&tb[d * 72 + ml];
                *(uint4*)(dst + vb0 + (size_t)d * N_ + nbase + ml) = w;
            }
            if (plane == 0) {
                asm volatile("s_waitcnt lgkmcnt(0)" ::: "memory");
                __builtin_amdgcn_sched_barrier(0);
            }
        }
    }
}

// ---------------------------------------------------------------------------
// K4: MFMA attention.  QBLK=128 (4 waves x 32q), KVBLK=64.
// 1D grid, XCD-swizzled so each bh's 16 q-blocks are co-resident on one XCD
// (K/V L2 reuse).  All inputs pre-split bf16 planes; staging = b128 copies.
// ---------------------------------------------------------------------------
__global__ __launch_bounds__(256, 3) void attn_k(
    const ushort* __restrict__ qhi, const ushort* __restrict__ qlo,
    const ushort* __restrict__ khi, const ushort* __restrict__ klo,
    const ushort* __restrict__ vthi, const ushort* __restrict__ vtlo,
    ushort* __restrict__ Ohi, ushort* __restrict__ Olo) {
    __shared__ __attribute__((aligned(16))) ushort Kh[64 * 64];
    __shared__ __attribute__((aligned(16))) ushort Kl[64 * 64];
    __shared__ __attribute__((aligned(16))) ushort Vh[64 * 64];
    __shared__ __attribute__((aligned(16))) ushort Vl[64 * 64];
    __shared__ __attribute__((aligned(16))) ushort Pbuf[4][32 * 64];

    const int hw = blockIdx.x;
    const int lg = ((hw & 7) << 7) | (hw >> 3);    // XCD swizzle (1024 wgs)
    const int bh = lg >> 4;
    const int q0 = (lg & 15) << 7;
    const int tid = threadIdx.x;
    const int ws = tid >> 6;
    const int lo5 = tid & 31;
    const int hi5 = (tid & 63) >> 5;
    const size_t base = (size_t)bh * (N_ * DHEAD);
    const ushort* khp = khi + base;
    const ushort* klp = klo + base;
    const ushort* vhp = vthi + base;   // [d][n] rows of N_
    const ushort* vlp = vtlo + base;
    const int srow = tid >> 2;         // staging row 0..63
    const int scc = (tid & 3) * 16;    // staging col chunk

    // ---- Q fragments (pre-scaled, pre-split) ----
    const int qrow0 = q0 + ws * 32;
    const size_t qbase = base + (size_t)(qrow0 + lo5) * DHEAD;
    s8v qh[4], ql[4];
#pragma unroll
    for (int s = 0; s < 4; ++s) {
        const int d0 = 16 * s + 8 * hi5;
        qh[s] = *(const s8v*)(qhi + qbase + d0);
        ql[s] = *(const s8v*)(qlo + qbase + d0);
    }

    f16v o0 = {0,0,0,0,0,0,0,0,0,0,0,0,0,0,0,0};
    f16v o1 = {0,0,0,0,0,0,0,0,0,0,0,0,0,0,0,0};
    float dsum[16];
#pragma unroll
    for (int r = 0; r < 16; ++r) dsum[r] = 0.0f;
    ushort* Pw = Pbuf[ws];

    uint4 pre[8];
#define LDTILE(kt_)                                                            \
    {                                                                          \
        const size_t kr = (size_t)((kt_) * 64 + srow) * 64 + scc;              \
        pre[0] = *(const uint4*)(khp + kr); pre[1] = *(const uint4*)(khp + kr + 8); \
        pre[2] = *(const uint4*)(klp + kr); pre[3] = *(const uint4*)(klp + kr + 8); \
        const size_t vr = (size_t)srow * N_ + (kt_) * 64 + scc;                \
        pre[4] = *(const uint4*)(vhp + vr); pre[5] = *(const uint4*)(vhp + vr + 8); \
        pre[6] = *(const uint4*)(vlp + vr); pre[7] = *(const uint4*)(vlp + vr + 8); \
    }

    LDTILE(0)
    const int sb0 = swz8(srow, scc), sb1 = swz8(srow, scc + 8);
    for (int kt = 0; kt < N_ / 64; ++kt) {
        __syncthreads();
        *(uint4*)&Kh[sb0] = pre[0]; *(uint4*)&Kh[sb1] = pre[1];
        *(uint4*)&Kl[sb0] = pre[2]; *(uint4*)&Kl[sb1] = pre[3];
        *(uint4*)&Vh[sb0] = pre[4]; *(uint4*)&Vh[sb1] = pre[5];
        *(uint4*)&Vl[sb0] = pre[6]; *(uint4*)&Vl[sb1] = pre[7];
        __syncthreads();
        if (kt + 1 < N_ / 64) LDTILE(kt + 1)
        // ---- S = QK^T, 3-term split ----
        f16v s0 = {0,0,0,0,0,0,0,0,0,0,0,0,0,0,0,0};
        f16v s1 = {0,0,0,0,0,0,0,0,0,0,0,0,0,0,0,0};
#pragma unroll
        for (int s = 0; s < 4; ++s) {
            const int d0 = 16 * s + 8 * hi5;
            const s8v b0h = *(const s8v*)&Kh[swz8(lo5, d0)];
            const s8v b0l = *(const s8v*)&Kl[swz8(lo5, d0)];
            const s8v b1h = *(const s8v*)&Kh[swz8(32 + lo5, d0)];
            const s8v b1l = *(const s8v*)&Kl[swz8(32 + lo5, d0)];
            s0 = MFMA(qh[s], b0h, s0);
            s1 = MFMA(qh[s], b1h, s1);
            s0 = MFMA(ql[s], b0h, s0);
            s1 = MFMA(ql[s], b1h, s1);
            s0 = MFMA(qh[s], b0l, s0);
            s1 = MFMA(qh[s], b1l, s1);
        }
        // ---- P = bf16(exp(min(S,50))); denom from rounded P ----
#pragma unroll
        for (int r = 0; r < 16; ++r) {
            const float p0 = __expf(fminf(s0[r], 50.0f));
            const float p1 = __expf(fminf(s1[r], 50.0f));
            const ushort h0 = f2bf(p0);
            const ushort h1 = f2bf(p1);
            dsum[r] += bf2f(h0) + bf2f(h1);
            const int qr = (r & 3) + 8 * (r >> 2) + 4 * hi5;
            Pw[swz8(qr, lo5)] = h0;
            Pw[swz8(qr, 32 + lo5)] = h1;
        }
        // rule #18: drain per-wave P LDS writes; pin scheduler.
        asm volatile("s_waitcnt lgkmcnt(0)" ::: "memory");
        __builtin_amdgcn_sched_barrier(0);
        // ---- O += P V ----
#pragma unroll
        for (int s = 0; s < 4; ++s) {
            const int koff = 16 * s + 8 * hi5;
            BF8 pah;
            pah.q[0] = *(const u64*)&Pw[swz8(lo5, koff)];
            pah.q[1] = *(const u64*)&Pw[swz8(lo5, koff) + 4];
            const s8v v0h = *(const s8v*)&Vh[swz8(lo5, koff)];
            const s8v v0l = *(const s8v*)&Vl[swz8(lo5, koff)];
            const s8v v1h = *(const s8v*)&Vh[swz8(32 + lo5, koff)];
            const s8v v1l = *(const s8v*)&Vl[swz8(32 + lo5, koff)];
            o0 = MFMA(pah.v, v0h, o0);
            o1 = MFMA(pah.v, v1h, o1);
            o0 = MFMA(pah.v, v0l, o0);
            o1 = MFMA(pah.v, v1l, o1);
        }
    }
#pragma unroll
    for (int r = 0; r < 16; ++r) {
#pragma unroll
        for (int off = 1; off < 32; off <<= 1)
            dsum[r] += __shfl_xor(dsum[r], off);
    }
    const int b = bh >> 3, hh = bh & 7;
#pragma unroll
    for (int r = 0; r < 16; ++r) {
        const int qr = (r & 3) + 8 * (r >> 2) + 4 * hi5;
        const float inv = 1.0f / dsum[r];
        const size_t rowb = ((size_t)b * N_ + qrow0 + qr) * DIM + hh * DHEAD;
        ushort h, l;
        split2(o0[r] * inv, h, l);
        Ohi[rowb + lo5] = h;      Olo[rowb + lo5] = l;
        split2(o1[r] * inv, h, l);
        Ohi[rowb + 32 + lo5] = h; Olo[rowb + 32 + lo5] = l;
    }
}

// ---------------------------------------------------------------------------
// K5: out GEMM (split-bf16 MFMA), plain f32 store.  XCD-swizzled 1D grid.
// ---------------------------------------------------------------------------
__global__ __launch_bounds__(256, 2) void out_gemm_k(
    const ushort* __restrict__ Ahi, const ushort* __restrict__ Alo,
    const ushort* __restrict__ Bhi, const ushort* __restrict__ Blo,
    float* __restrict__ out) {
    __shared__ __attribute__((aligned(16))) ushort pool[4 * 128 * 36];
    ushort* Ah = pool;
    ushort* Al = pool + 4608;
    ushort* Bh = pool + 9216;
    ushort* Bl = pool + 13824;
    const int hw = blockIdx.x;
    const int lg = ((hw & 7) << 6) | (hw >> 3);    // XCD swizzle (512 wgs)
    const int row0 = (lg >> 2) * 128;
    const int col0 = (lg & 3) * 128;
    const int tid = threadIdx.x;
    const int wv = tid >> 6;
    const int wy = wv >> 1, wx = wv & 1;
    const int lo5 = tid & 31;
    const int hi5 = (tid & 63) >> 5;
    const int sr = tid >> 1;
    const int sh = (tid & 1) * 16;

    f16v acc[2][2];
#pragma unroll
    for (int i = 0; i < 2; ++i)
#pragma unroll
        for (int j = 0; j < 2; ++j)
#pragma unroll
            for (int r = 0; r < 16; ++r) acc[i][j][r] = 0.0f;

    uint4 ra[2][2], rb[2][2];
    const size_t abase = (size_t)(row0 + sr) * DIM + sh;
    const size_t bbase = (size_t)(col0 + sr) * DIM + sh;
    ra[0][0] = *(const uint4*)(Ahi + abase);  ra[0][1] = *(const uint4*)(Ahi + abase + 8);
    ra[1][0] = *(const uint4*)(Alo + abase);  ra[1][1] = *(const uint4*)(Alo + abase + 8);
    rb[0][0] = *(const uint4*)(Bhi + bbase);  rb[0][1] = *(const uint4*)(Bhi + bbase + 8);
    rb[1][0] = *(const uint4*)(Blo + bbase);  rb[1][1] = *(const uint4*)(Blo + bbase + 8);

    const int sbase = sr * 36 + sh;
    for (int k0 = 0; k0 < DIM; k0 += 32) {
        __syncthreads();
        *(uint4*)&Ah[sbase] = ra[0][0]; *(uint4*)&Ah[sbase + 8] = ra[0][1];
        *(uint4*)&Al[sbase] = ra[1][0]; *(uint4*)&Al[sbase + 8] = ra[1][1];
        *(uint4*)&Bh[sbase] = rb[0][0]; *(uint4*)&Bh[sbase + 8] = rb[0][1];
        *(uint4*)&Bl[sbase] = rb[1][0]; *(uint4*)&Bl[sbase + 8] = rb[1][1];
        __syncthreads();
        if (k0 + 32 < DIM) {
            const size_t a2 = abase + k0 + 32, b2 = bbase + k0 + 32;
            ra[0][0] = *(const uint4*)(Ahi + a2); ra[0][1] = *(const uint4*)(Ahi + a2 + 8);
            ra[1][0] = *(const uint4*)(Alo + a2); ra[1][1] = *(const uint4*)(Alo + a2 + 8);
            rb[0][0] = *(const uint4*)(Bhi + b2); rb[0][1] = *(const uint4*)(Bhi + b2 + 8);
            rb[1][0] = *(const uint4*)(Blo + b2); rb[1][1] = *(const uint4*)(Blo + b2 + 8);
        }
#pragma unroll
        for (int ks = 0; ks < 2; ++ks) {
            s8v a_h[2], a_l[2], b_h[2], b_l[2];
#pragma unroll
            for (int rt = 0; rt < 2; ++rt) {
                const int off = (wy * 64 + rt * 32 + lo5) * 36 + ks * 16 + 8 * hi5;
                BF8 th, tl;
                th.q[0] = *(const u64*)&Ah[off]; th.q[1] = *(const u64*)&Ah[off + 4];
                tl.q[0] = *(const u64*)&Al[off]; tl.q[1] = *(const u64*)&Al[off + 4];
                a_h[rt] = th.v; a_l[rt] = tl.v;
            }
#pragma unroll
            for (int ct = 0; ct < 2; ++ct) {
                const int off = (wx * 64 + ct * 32 + lo5) * 36 + ks * 16 + 8 * hi5;
                BF8 th, tl;
                th.q[0] = *(const u64*)&Bh[off]; th.q[1] = *(const u64*)&Bh[off + 4];
                tl.q[0] = *(const u64*)&Bl[off]; tl.q[1] = *(const u64*)&Bl[off + 4];
                b_h[ct] = th.v; b_l[ct] = tl.v;
            }
#pragma unroll
            for (int rt = 0; rt < 2; ++rt)
#pragma unroll
                for (int ct = 0; ct < 2; ++ct) {
                    acc[rt][ct] = MFMA(a_h[rt], b_h[ct], acc[rt][ct]);
                    acc[rt][ct] = MFMA(a_l[rt], b_h[ct], acc[rt][ct]);
                    acc[rt][ct] = MFMA(a_h[rt], b_l[ct], acc[rt][ct]);
                }
        }
    }
#pragma unroll
    for (int rt = 0; rt < 2; ++rt)
#pragma unroll
        for (int ct = 0; ct < 2; ++ct) {
            const int c = col0 + wx * 64 + ct * 32 + lo5;
#pragma unroll
            for (int r = 0; r < 16; ++r) {
                const int m = row0 + wy * 64 + rt * 32 + (r & 3) + 8 * (r >> 2) + 4 * hi5;
                out[(size_t)m * DIM + c] = acc[rt][ct][r];
            }
        }
}

// ---------------------------------------------------------------------------
extern "C" void kernel_launch(void* const* d_in, const int* in_sizes, int n_in,
                              void* d_out, int out_size, void* d_ws, size_t ws_size,
                              hipStream_t stream) {
    const float* x       = (const float*)d_in[0];
    const float* g       = (const float*)d_in[1];
    const float* w_qkv   = (const float*)d_in[2];
    const float* q_scale = (const float*)d_in[3];
    const float* k_scale = (const float*)d_in[4];
    const float* w_out   = (const float*)d_in[5];
    float* out = (float*)d_out;

    if (ws_size < 8 * MB16) return;   // need 128 MiB scratch

    char* W = (char*)d_ws;
    ushort* xnhi = (ushort*)W;                  // 16MB each
    ushort* xnlo = (ushort*)(W + MB16);
    ushort* qhi  = (ushort*)(W + 2 * MB16);
    ushort* qlo  = (ushort*)(W + 3 * MB16);
    ushort* khi  = (ushort*)(W + 4 * MB16);
    ushort* klo  = (ushort*)(W + 5 * MB16);
    ushort* vthi = (ushort*)(W + 6 * MB16);
    ushort* vtlo = (ushort*)(W + 7 * MB16);
    ushort* Ohi  = xnhi;                        // reuse (xn dead after gemm0)
    ushort* Olo  = xnlo;
    ushort* wqh = (ushort*)d_out;               // d_out scratch until out_gemm
    ushort* wql = wqh + (size_t)1536 * 512;
    ushort* woh = qhi;                          // q dead after attn
    ushort* wol = qhi + (size_t)512 * 512;

    split_w_k<<<dim3(48, 16), 256, 0, stream>>>(w_qkv, wqh, wql, 512, 1536);
    rmsnorm_k<<<TOKENS / 4, 256, 0, stream>>>(x, g, xnhi, xnlo);
    qkv_gemm_k<<<1536, 256, 0, stream>>>(
        xnhi, xnlo, wqh, wql, q_scale, k_scale,
        qhi, qlo, khi, klo, vthi, vtlo);
    attn_k<<<1024, 256, 0, stream>>>(
        qhi, qlo, khi, klo, vthi, vtlo, Ohi, Olo);
    split_w_k<<<dim3(16, 16), 256, 0, stream>>>(w_out, woh, wol, 512, 512);
    out_gemm_k<<<512, 256, 0, stream>>>(Ohi, Olo, woh, wol, out);
}

// Round 9
// 792.113 us; speedup vs baseline: 1.5606x; 1.3770x over previous
//
#include <hip/hip_runtime.h>
#include <math.h>

#define B_ 8
#define N_ 2048
#define DIM 512
#define HEADS 8
#define DHEAD 64
#define TOKENS (B_ * N_)                 // 16384
#define SCALE_ 8.0f
#define EPS_ 1e-12f
#define SQRT_DIM 22.62741699796952f      // sqrt(512)
#define MB16 ((size_t)16 * 1024 * 1024)

typedef unsigned long long u64;
typedef __attribute__((ext_vector_type(8))) short s8v;     // 8 bf16 (4 VGPR)
typedef __attribute__((ext_vector_type(16))) float f16v;   // MFMA 32x32 acc

#define MFMA(a, b, c) __builtin_amdgcn_mfma_f32_32x32x16_bf16(a, b, c, 0, 0, 0)

__device__ __forceinline__ ushort f2bf(float f) {
    uint u = __float_as_uint(f);
    return (ushort)((u + 0x7FFFu + ((u >> 16) & 1u)) >> 16);
}
__device__ __forceinline__ float bf2f(ushort h) {
    return __uint_as_float(((uint)h) << 16);
}
__device__ __forceinline__ void split2(float x, ushort& h, ushort& l) {
    h = f2bf(x);
    l = f2bf(x - bf2f(h));
}

union BF8 { u64 q[2]; ushort us[8]; s8v v; };

// attn LDS swizzle, 8-ushort granular: every access stays one b128 op.
__device__ __forceinline__ int swz8(int row, int col) {
    return row * 64 + (col ^ ((row & 7) << 3));
}

// ---------------------------------------------------------------------------
// K0: transpose + split  W[K][N] f32  ->  WT_hi / WT_lo [N][K] bf16 planes.
// ---------------------------------------------------------------------------
__global__ __launch_bounds__(256) void split_w_k(const float* __restrict__ W,
                                                 ushort* __restrict__ WThi,
                                                 ushort* __restrict__ WTlo,
                                                 int K, int N) {
    __shared__ float T[32][33];
    const int k0 = blockIdx.y * 32, n0 = blockIdx.x * 32;
    const int tr = threadIdx.x >> 5;
    const int tc = threadIdx.x & 31;
#pragma unroll
    for (int i = 0; i < 4; ++i)
        T[tr + 8 * i][tc] = W[(size_t)(k0 + tr + 8 * i) * N + n0 + tc];
    __syncthreads();
#pragma unroll
    for (int i = 0; i < 4; ++i) {
        const int n = tr + 8 * i;
        ushort h, l;
        split2(T[tc][n], h, l);
        WThi[(size_t)(n0 + n) * K + k0 + tc] = h;
        WTlo[(size_t)(n0 + n) * K + k0 + tc] = l;
    }
}

// ---------------------------------------------------------------------------
// K1: RMSNorm -> hi/lo bf16 planes [token][512].
// ---------------------------------------------------------------------------
__global__ __launch_bounds__(256) void rmsnorm_k(const float* __restrict__ x,
                                                 const float* __restrict__ g,
                                                 ushort* __restrict__ xnhi,
                                                 ushort* __restrict__ xnlo) {
    const int wave = threadIdx.x >> 6;
    const int lane = threadIdx.x & 63;
    const size_t t = (size_t)blockIdx.x * 4 + wave;
    const float4* xp = (const float4*)(x + t * DIM + lane * 8);
    float4 v0 = xp[0], v1 = xp[1];
    float ss = v0.x * v0.x + v0.y * v0.y + v0.z * v0.z + v0.w * v0.w +
               v1.x * v1.x + v1.y * v1.y + v1.z * v1.z + v1.w * v1.w;
#pragma unroll
    for (int off = 32; off; off >>= 1) ss += __shfl_xor(ss, off);
    const float s = SQRT_DIM / fmaxf(sqrtf(ss), EPS_);
    const float4* gp = (const float4*)(g + lane * 8);
    float4 g0 = gp[0], g1 = gp[1];
    float ov[8] = {v0.x * s * g0.x, v0.y * s * g0.y, v0.z * s * g0.z,
                   v0.w * s * g0.w, v1.x * s * g1.x, v1.y * s * g1.y,
                   v1.z * s * g1.z, v1.w * s * g1.w};
    ushort h[8], l[8];
#pragma unroll
    for (int j = 0; j < 8; ++j) split2(ov[j], h[j], l[j]);
    uint4 H, L;
    H.x = (uint)h[0] | ((uint)h[1] << 16); H.y = (uint)h[2] | ((uint)h[3] << 16);
    H.z = (uint)h[4] | ((uint)h[5] << 16); H.w = (uint)h[6] | ((uint)h[7] << 16);
    L.x = (uint)l[0] | ((uint)l[1] << 16); L.y = (uint)l[2] | ((uint)l[3] << 16);
    L.z = (uint)l[4] | ((uint)l[5] << 16); L.w = (uint)l[6] | ((uint)l[7] << 16);
    *(uint4*)(xnhi + t * DIM + lane * 8) = H;
    *(uint4*)(xnlo + t * DIM + lane * 8) = L;
}

// ---------------------------------------------------------------------------
// K2: QKV GEMM (split-bf16 MFMA) + fused epilogue.
//   q,k: per-head l2norm + scale (+x8 into q), split -> [B,H,N,64] planes.
//   v:   LDS-transposed -> coalesced [B,H,64,N] plane stores (128B segments).
// Grid: 1536 blocks 1D, XCD-swizzled.  Tile 128x128, BK=32, 4 waves.
// ---------------------------------------------------------------------------
__global__ __launch_bounds__(256, 2) void qkv_gemm_k(
    const ushort* __restrict__ Ahi, const ushort* __restrict__ Alo,
    const ushort* __restrict__ Bhi, const ushort* __restrict__ Blo,
    const float* __restrict__ q_scale, const float* __restrict__ k_scale,
    ushort* __restrict__ qhi, ushort* __restrict__ qlo,
    ushort* __restrict__ khi, ushort* __restrict__ klo,
    ushort* __restrict__ vthi, ushort* __restrict__ vtlo) {
    __shared__ __attribute__((aligned(16))) ushort pool[4 * 128 * 36];
    ushort* Ah = pool;
    ushort* Al = pool + 4608;
    ushort* Bh = pool + 9216;
    ushort* Bl = pool + 13824;

    const int hw = blockIdx.x;
    const int lg = (hw & 7) * 192 + (hw >> 3);     // XCD swizzle (1536 wgs)
    const int bx = lg % 12;
    const int by = lg / 12;
    const int row0 = by * 128;
    const int col0 = bx * 128;
    const int tid = threadIdx.x;
    const int lane = tid & 63;
    const int wv = tid >> 6;
    const int wy = wv >> 1, wx = wv & 1;
    const int lo5 = tid & 31;
    const int hi5 = (tid & 63) >> 5;
    const int sr = tid >> 1;
    const int sh = (tid & 1) * 16;

    f16v acc[2][2];
#pragma unroll
    for (int i = 0; i < 2; ++i)
#pragma unroll
        for (int j = 0; j < 2; ++j)
#pragma unroll
            for (int r = 0; r < 16; ++r) acc[i][j][r] = 0.0f;

    uint4 ra[2][2], rb[2][2];
    const size_t abase = (size_t)(row0 + sr) * DIM + sh;
    const size_t bbase = (size_t)(col0 + sr) * DIM + sh;
    ra[0][0] = *(const uint4*)(Ahi + abase);  ra[0][1] = *(const uint4*)(Ahi + abase + 8);
    ra[1][0] = *(const uint4*)(Alo + abase);  ra[1][1] = *(const uint4*)(Alo + abase + 8);
    rb[0][0] = *(const uint4*)(Bhi + bbase);  rb[0][1] = *(const uint4*)(Bhi + bbase + 8);
    rb[1][0] = *(const uint4*)(Blo + bbase);  rb[1][1] = *(const uint4*)(Blo + bbase + 8);

    const int sbase = sr * 36 + sh;
    for (int k0 = 0; k0 < DIM; k0 += 32) {
        __syncthreads();
        *(uint4*)&Ah[sbase] = ra[0][0]; *(uint4*)&Ah[sbase + 8] = ra[0][1];
        *(uint4*)&Al[sbase] = ra[1][0]; *(uint4*)&Al[sbase + 8] = ra[1][1];
        *(uint4*)&Bh[sbase] = rb[0][0]; *(uint4*)&Bh[sbase + 8] = rb[0][1];
        *(uint4*)&Bl[sbase] = rb[1][0]; *(uint4*)&Bl[sbase + 8] = rb[1][1];
        __syncthreads();
        if (k0 + 32 < DIM) {
            const size_t a2 = abase + k0 + 32, b2 = bbase + k0 + 32;
            ra[0][0] = *(const uint4*)(Ahi + a2); ra[0][1] = *(const uint4*)(Ahi + a2 + 8);
            ra[1][0] = *(const uint4*)(Alo + a2); ra[1][1] = *(const uint4*)(Alo + a2 + 8);
            rb[0][0] = *(const uint4*)(Bhi + b2); rb[0][1] = *(const uint4*)(Bhi + b2 + 8);
            rb[1][0] = *(const uint4*)(Blo + b2); rb[1][1] = *(const uint4*)(Blo + b2 + 8);
        }
#pragma unroll
        for (int ks = 0; ks < 2; ++ks) {
            s8v a_h[2], a_l[2], b_h[2], b_l[2];
#pragma unroll
            for (int rt = 0; rt < 2; ++rt) {
                const int off = (wy * 64 + rt * 32 + lo5) * 36 + ks * 16 + 8 * hi5;
                BF8 th, tl;
                th.q[0] = *(const u64*)&Ah[off]; th.q[1] = *(const u64*)&Ah[off + 4];
                tl.q[0] = *(const u64*)&Al[off]; tl.q[1] = *(const u64*)&Al[off + 4];
                a_h[rt] = th.v; a_l[rt] = tl.v;
            }
#pragma unroll
            for (int ct = 0; ct < 2; ++ct) {
                const int off = (wx * 64 + ct * 32 + lo5) * 36 + ks * 16 + 8 * hi5;
                BF8 th, tl;
                th.q[0] = *(const u64*)&Bh[off]; th.q[1] = *(const u64*)&Bh[off + 4];
                tl.q[0] = *(const u64*)&Bl[off]; tl.q[1] = *(const u64*)&Bl[off + 4];
                b_h[ct] = th.v; b_l[ct] = tl.v;
            }
            __builtin_amdgcn_s_setprio(1);
#pragma unroll
            for (int rt = 0; rt < 2; ++rt)
#pragma unroll
                for (int ct = 0; ct < 2; ++ct) {
                    acc[rt][ct] = MFMA(a_h[rt], b_h[ct], acc[rt][ct]);
                    acc[rt][ct] = MFMA(a_l[rt], b_h[ct], acc[rt][ct]);
                    acc[rt][ct] = MFMA(a_h[rt], b_l[ct], acc[rt][ct]);
                }
            __builtin_amdgcn_s_setprio(0);
        }
    }
    // ---- fused epilogue ----
    const int which = col0 >> 9;          // block-uniform: 0=q 1=k 2=v
    const int c64 = col0 + wx * 64;
    const int h = (c64 & 511) >> 6;       // head (uniform per wave)
    if (which < 2) {
        const float* sc = which ? k_scale : q_scale;
        const float s0c = sc[lo5], s1c = sc[32 + lo5];
        ushort* Dh = which ? khi : qhi;
        ushort* Dl = which ? klo : qlo;
        const float mul = which ? 1.0f : SCALE_;   // fold softmax x8 into q
#pragma unroll
        for (int rt = 0; rt < 2; ++rt)
#pragma unroll
            for (int r = 0; r < 16; ++r) {
                float v0 = acc[rt][0][r], v1 = acc[rt][1][r];
                float ss = v0 * v0 + v1 * v1;
#pragma unroll
                for (int off = 16; off; off >>= 1) ss += __shfl_xor(ss, off);
                const float inv = mul / fmaxf(sqrtf(ss), EPS_);
                v0 *= inv * s0c; v1 *= inv * s1c;
                const int m = row0 + wy * 64 + rt * 32 + (r & 3) + 8 * (r >> 2) + 4 * hi5;
                const int b = m >> 11, n = m & 2047;
                const size_t rb_ = (((size_t)b * HEADS + h) * N_ + n) * DHEAD;
                ushort hh, ll;
                split2(v0, hh, ll); Dh[rb_ + lo5] = hh;      Dl[rb_ + lo5] = ll;
                split2(v1, hh, ll); Dh[rb_ + 32 + lo5] = hh; Dl[rb_ + 32 + lo5] = ll;
            }
    } else {
        // V: per-wave LDS transpose (reuse staging pool) -> coalesced stores.
        __syncthreads();                       // staging pool now reusable
        ushort* tb = pool + wv * (64 * 72);    // [64 d][72 stride] ushorts
        const int bB = row0 >> 11;
        const int nbase = (row0 & 2047) + wy * 64;   // within-batch token
        const size_t vb0 = (((size_t)bB * HEADS + h) * DHEAD) * (size_t)N_;
#pragma unroll
        for (int plane = 0; plane < 2; ++plane) {
#pragma unroll
            for (int rt = 0; rt < 2; ++rt)
#pragma unroll
                for (int ct = 0; ct < 2; ++ct)
#pragma unroll
                    for (int r = 0; r < 16; ++r) {
                        ushort hh, ll;
                        split2(acc[rt][ct][r], hh, ll);
                        const int ml = rt * 32 + (r & 3) + 8 * (r >> 2) + 4 * hi5;
                        const int dl = ct * 32 + lo5;
                        tb[dl * 72 + ml] = plane ? ll : hh;
                    }
            asm volatile("s_waitcnt lgkmcnt(0)" ::: "memory");
            __builtin_amdgcn_sched_barrier(0);
            ushort* dst = plane ? vtlo : vthi;
#pragma unroll
            for (int i = 0; i < 8; ++i) {
                const int d = (lane >> 3) + 8 * i;
                const int ml = (lane & 7) * 8;
                uint4 w = *(const uint4*)&tb[d * 72 + ml];
                *(uint4*)(dst + vb0 + (size_t)d * N_ + nbase + ml) = w;
            }
            if (plane == 0) {
                asm volatile("s_waitcnt lgkmcnt(0)" ::: "memory");
                __builtin_amdgcn_sched_barrier(0);
            }
        }
    }
}

// ---------------------------------------------------------------------------
// K4: MFMA attention.  QBLK=128 (4 waves x 32q), KVBLK=64.
// 1D grid, XCD-swizzled so each bh's 16 q-blocks are co-resident on one XCD.
// __launch_bounds__(256, 2): VGPR budget 256 -> NO SPILLS (R8's (256,3) cut
// the budget to ~170 and spilled the pre[8] prefetch -> 900MB scratch writes).
// Occupancy still ~3 blocks/CU via the 48KB LDS cap.
// ---------------------------------------------------------------------------
__global__ __launch_bounds__(256, 2) void attn_k(
    const ushort* __restrict__ qhi, const ushort* __restrict__ qlo,
    const ushort* __restrict__ khi, const ushort* __restrict__ klo,
    const ushort* __restrict__ vthi, const ushort* __restrict__ vtlo,
    ushort* __restrict__ Ohi, ushort* __restrict__ Olo) {
    __shared__ __attribute__((aligned(16))) ushort Kh[64 * 64];
    __shared__ __attribute__((aligned(16))) ushort Kl[64 * 64];
    __shared__ __attribute__((aligned(16))) ushort Vh[64 * 64];
    __shared__ __attribute__((aligned(16))) ushort Vl[64 * 64];
    __shared__ __attribute__((aligned(16))) ushort Pbuf[4][32 * 64];

    const int hw = blockIdx.x;
    const int lg = ((hw & 7) << 7) | (hw >> 3);    // XCD swizzle (1024 wgs)
    const int bh = lg >> 4;
    const int q0 = (lg & 15) << 7;
    const int tid = threadIdx.x;
    const int ws = tid >> 6;
    const int lo5 = tid & 31;
    const int hi5 = (tid & 63) >> 5;
    const size_t base = (size_t)bh * (N_ * DHEAD);
    const ushort* khp = khi + base;
    const ushort* klp = klo + base;
    const ushort* vhp = vthi + base;   // [d][n] rows of N_
    const ushort* vlp = vtlo + base;
    const int srow = tid >> 2;         // staging row 0..63
    const int scc = (tid & 3) * 16;    // staging col chunk

    // ---- Q fragments (pre-scaled, pre-split) ----
    const int qrow0 = q0 + ws * 32;
    const size_t qbase = base + (size_t)(qrow0 + lo5) * DHEAD;
    s8v qh[4], ql[4];
#pragma unroll
    for (int s = 0; s < 4; ++s) {
        const int d0 = 16 * s + 8 * hi5;
        qh[s] = *(const s8v*)(qhi + qbase + d0);
        ql[s] = *(const s8v*)(qlo + qbase + d0);
    }

    f16v o0 = {0,0,0,0,0,0,0,0,0,0,0,0,0,0,0,0};
    f16v o1 = {0,0,0,0,0,0,0,0,0,0,0,0,0,0,0,0};
    float dsum[16];
#pragma unroll
    for (int r = 0; r < 16; ++r) dsum[r] = 0.0f;
    ushort* Pw = Pbuf[ws];

    uint4 pre[8];
#define LDTILE(kt_)                                                            \
    {                                                                          \
        const size_t kr = (size_t)((kt_) * 64 + srow) * 64 + scc;              \
        pre[0] = *(const uint4*)(khp + kr); pre[1] = *(const uint4*)(khp + kr + 8); \
        pre[2] = *(const uint4*)(klp + kr); pre[3] = *(const uint4*)(klp + kr + 8); \
        const size_t vr = (size_t)srow * N_ + (kt_) * 64 + scc;                \
        pre[4] = *(const uint4*)(vhp + vr); pre[5] = *(const uint4*)(vhp + vr + 8); \
        pre[6] = *(const uint4*)(vlp + vr); pre[7] = *(const uint4*)(vlp + vr + 8); \
    }

    LDTILE(0)
    const int sb0 = swz8(srow, scc), sb1 = swz8(srow, scc + 8);
    for (int kt = 0; kt < N_ / 64; ++kt) {
        __syncthreads();
        *(uint4*)&Kh[sb0] = pre[0]; *(uint4*)&Kh[sb1] = pre[1];
        *(uint4*)&Kl[sb0] = pre[2]; *(uint4*)&Kl[sb1] = pre[3];
        *(uint4*)&Vh[sb0] = pre[4]; *(uint4*)&Vh[sb1] = pre[5];
        *(uint4*)&Vl[sb0] = pre[6]; *(uint4*)&Vl[sb1] = pre[7];
        __syncthreads();
        if (kt + 1 < N_ / 64) LDTILE(kt + 1)
        // ---- S = QK^T, 3-term split ----
        f16v s0 = {0,0,0,0,0,0,0,0,0,0,0,0,0,0,0,0};
        f16v s1 = {0,0,0,0,0,0,0,0,0,0,0,0,0,0,0,0};
#pragma unroll
        for (int s = 0; s < 4; ++s) {
            const int d0 = 16 * s + 8 * hi5;
            const s8v b0h = *(const s8v*)&Kh[swz8(lo5, d0)];
            const s8v b0l = *(const s8v*)&Kl[swz8(lo5, d0)];
            const s8v b1h = *(const s8v*)&Kh[swz8(32 + lo5, d0)];
            const s8v b1l = *(const s8v*)&Kl[swz8(32 + lo5, d0)];
            __builtin_amdgcn_s_setprio(1);
            s0 = MFMA(qh[s], b0h, s0);
            s1 = MFMA(qh[s], b1h, s1);
            s0 = MFMA(ql[s], b0h, s0);
            s1 = MFMA(ql[s], b1h, s1);
            s0 = MFMA(qh[s], b0l, s0);
            s1 = MFMA(qh[s], b1l, s1);
            __builtin_amdgcn_s_setprio(0);
        }
        // ---- P = bf16(exp(min(S,50))); denom from rounded P ----
#pragma unroll
        for (int r = 0; r < 16; ++r) {
            const float p0 = __expf(fminf(s0[r], 50.0f));
            const float p1 = __expf(fminf(s1[r], 50.0f));
            const ushort h0 = f2bf(p0);
            const ushort h1 = f2bf(p1);
            dsum[r] += bf2f(h0) + bf2f(h1);
            const int qr = (r & 3) + 8 * (r >> 2) + 4 * hi5;
            Pw[swz8(qr, lo5)] = h0;
            Pw[swz8(qr, 32 + lo5)] = h1;
        }
        // rule #18: drain per-wave P LDS writes; pin scheduler.
        asm volatile("s_waitcnt lgkmcnt(0)" ::: "memory");
        __builtin_amdgcn_sched_barrier(0);
        // ---- O += P V ----
#pragma unroll
        for (int s = 0; s < 4; ++s) {
            const int koff = 16 * s + 8 * hi5;
            BF8 pah;
            pah.q[0] = *(const u64*)&Pw[swz8(lo5, koff)];
            pah.q[1] = *(const u64*)&Pw[swz8(lo5, koff) + 4];
            const s8v v0h = *(const s8v*)&Vh[swz8(lo5, koff)];
            const s8v v0l = *(const s8v*)&Vl[swz8(lo5, koff)];
            const s8v v1h = *(const s8v*)&Vh[swz8(32 + lo5, koff)];
            const s8v v1l = *(const s8v*)&Vl[swz8(32 + lo5, koff)];
            __builtin_amdgcn_s_setprio(1);
            o0 = MFMA(pah.v, v0h, o0);
            o1 = MFMA(pah.v, v1h, o1);
            o0 = MFMA(pah.v, v0l, o0);
            o1 = MFMA(pah.v, v1l, o1);
            __builtin_amdgcn_s_setprio(0);
        }
    }
#pragma unroll
    for (int r = 0; r < 16; ++r) {
#pragma unroll
        for (int off = 1; off < 32; off <<= 1)
            dsum[r] += __shfl_xor(dsum[r], off);
    }
    const int b = bh >> 3, hh = bh & 7;
#pragma unroll
    for (int r = 0; r < 16; ++r) {
        const int qr = (r & 3) + 8 * (r >> 2) + 4 * hi5;
        const float inv = 1.0f / dsum[r];
        const size_t rowb = ((size_t)b * N_ + qrow0 + qr) * DIM + hh * DHEAD;
        ushort h, l;
        split2(o0[r] * inv, h, l);
        Ohi[rowb + lo5] = h;      Olo[rowb + lo5] = l;
        split2(o1[r] * inv, h, l);
        Ohi[rowb + 32 + lo5] = h; Olo[rowb + 32 + lo5] = l;
    }
}

// ---------------------------------------------------------------------------
// K5: out GEMM (split-bf16 MFMA), plain f32 store.  XCD-swizzled 1D grid.
// ---------------------------------------------------------------------------
__global__ __launch_bounds__(256, 2) void out_gemm_k(
    const ushort* __restrict__ Ahi, const ushort* __restrict__ Alo,
    const ushort* __restrict__ Bhi, const ushort* __restrict__ Blo,
    float* __restrict__ out) {
    __shared__ __attribute__((aligned(16))) ushort pool[4 * 128 * 36];
    ushort* Ah = pool;
    ushort* Al = pool + 4608;
    ushort* Bh = pool + 9216;
    ushort* Bl = pool + 13824;
    const int hw = blockIdx.x;
    const int lg = ((hw & 7) << 6) | (hw >> 3);    // XCD swizzle (512 wgs)
    const int row0 = (lg >> 2) * 128;
    const int col0 = (lg & 3) * 128;
    const int tid = threadIdx.x;
    const int wv = tid >> 6;
    const int wy = wv >> 1, wx = wv & 1;
    const int lo5 = tid & 31;
    const int hi5 = (tid & 63) >> 5;
    const int sr = tid >> 1;
    const int sh = (tid & 1) * 16;

    f16v acc[2][2];
#pragma unroll
    for (int i = 0; i < 2; ++i)
#pragma unroll
        for (int j = 0; j < 2; ++j)
#pragma unroll
            for (int r = 0; r < 16; ++r) acc[i][j][r] = 0.0f;

    uint4 ra[2][2], rb[2][2];
    const size_t abase = (size_t)(row0 + sr) * DIM + sh;
    const size_t bbase = (size_t)(col0 + sr) * DIM + sh;
    ra[0][0] = *(const uint4*)(Ahi + abase);  ra[0][1] = *(const uint4*)(Ahi + abase + 8);
    ra[1][0] = *(const uint4*)(Alo + abase);  ra[1][1] = *(const uint4*)(Alo + abase + 8);
    rb[0][0] = *(const uint4*)(Bhi + bbase);  rb[0][1] = *(const uint4*)(Bhi + bbase + 8);
    rb[1][0] = *(const uint4*)(Blo + bbase);  rb[1][1] = *(const uint4*)(Blo + bbase + 8);

    const int sbase = sr * 36 + sh;
    for (int k0 = 0; k0 < DIM; k0 += 32) {
        __syncthreads();
        *(uint4*)&Ah[sbase] = ra[0][0]; *(uint4*)&Ah[sbase + 8] = ra[0][1];
        *(uint4*)&Al[sbase] = ra[1][0]; *(uint4*)&Al[sbase + 8] = ra[1][1];
        *(uint4*)&Bh[sbase] = rb[0][0]; *(uint4*)&Bh[sbase + 8] = rb[0][1];
        *(uint4*)&Bl[sbase] = rb[1][0]; *(uint4*)&Bl[sbase + 8] = rb[1][1];
        __syncthreads();
        if (k0 + 32 < DIM) {
            const size_t a2 = abase + k0 + 32, b2 = bbase + k0 + 32;
            ra[0][0] = *(const uint4*)(Ahi + a2); ra[0][1] = *(const uint4*)(Ahi + a2 + 8);
            ra[1][0] = *(const uint4*)(Alo + a2); ra[1][1] = *(const uint4*)(Alo + a2 + 8);
            rb[0][0] = *(const uint4*)(Bhi + b2); rb[0][1] = *(const uint4*)(Bhi + b2 + 8);
            rb[1][0] = *(const uint4*)(Blo + b2); rb[1][1] = *(const uint4*)(Blo + b2 + 8);
        }
#pragma unroll
        for (int ks = 0; ks < 2; ++ks) {
            s8v a_h[2], a_l[2], b_h[2], b_l[2];
#pragma unroll
            for (int rt = 0; rt < 2; ++rt) {
                const int off = (wy * 64 + rt * 32 + lo5) * 36 + ks * 16 + 8 * hi5;
                BF8 th, tl;
                th.q[0] = *(const u64*)&Ah[off]; th.q[1] = *(const u64*)&Ah[off + 4];
                tl.q[0] = *(const u64*)&Al[off]; tl.q[1] = *(const u64*)&Al[off + 4];
                a_h[rt] = th.v; a_l[rt] = tl.v;
            }
#pragma unroll
            for (int ct = 0; ct < 2; ++ct) {
                const int off = (wx * 64 + ct * 32 + lo5) * 36 + ks * 16 + 8 * hi5;
                BF8 th, tl;
                th.q[0] = *(const u64*)&Bh[off]; th.q[1] = *(const u64*)&Bh[off + 4];
                tl.q[0] = *(const u64*)&Bl[off]; tl.q[1] = *(const u64*)&Bl[off + 4];
                b_h[ct] = th.v; b_l[ct] = tl.v;
            }
            __builtin_amdgcn_s_setprio(1);
#pragma unroll
            for (int rt = 0; rt < 2; ++rt)
#pragma unroll
                for (int ct = 0; ct < 2; ++ct) {
                    acc[rt][ct] = MFMA(a_h[rt], b_h[ct], acc[rt][ct]);
                    acc[rt][ct] = MFMA(a_l[rt], b_h[ct], acc[rt][ct]);
                    acc[rt][ct] = MFMA(a_h[rt], b_l[ct], acc[rt][ct]);
                }
            __builtin_amdgcn_s_setprio(0);
        }
    }
#pragma unroll
    for (int rt = 0; rt < 2; ++rt)
#pragma unroll
        for (int ct = 0; ct < 2; ++ct) {
            const int c = col0 + wx * 64 + ct * 32 + lo5;
#pragma unroll
            for (int r = 0; r < 16; ++r) {
                const int m = row0 + wy * 64 + rt * 32 + (r & 3) + 8 * (r >> 2) + 4 * hi5;
                out[(size_t)m * DIM + c] = acc[rt][ct][r];
            }
        }
}

// ---------------------------------------------------------------------------
extern "C" void kernel_launch(void* const* d_in, const int* in_sizes, int n_in,
                              void* d_out, int out_size, void* d_ws, size_t ws_size,
                              hipStream_t stream) {
    const float* x       = (const float*)d_in[0];
    const float* g       = (const float*)d_in[1];
    const float* w_qkv   = (const float*)d_in[2];
    const float* q_scale = (const float*)d_in[3];
    const float* k_scale = (const float*)d_in[4];
    const float* w_out   = (const float*)d_in[5];
    float* out = (float*)d_out;

    if (ws_size < 8 * MB16) return;   // need 128 MiB scratch

    char* W = (char*)d_ws;
    ushort* xnhi = (ushort*)W;                  // 16MB each
    ushort* xnlo = (ushort*)(W + MB16);
    ushort* qhi  = (ushort*)(W + 2 * MB16);
    ushort* qlo  = (ushort*)(W + 3 * MB16);
    ushort* khi  = (ushort*)(W + 4 * MB16);
    ushort* klo  = (ushort*)(W + 5 * MB16);
    ushort* vthi = (ushort*)(W + 6 * MB16);
    ushort* vtlo = (ushort*)(W + 7 * MB16);
    ushort* Ohi  = xnhi;                        // reuse (xn dead after gemm0)
    ushort* Olo  = xnlo;
    ushort* wqh = (ushort*)d_out;               // d_out scratch until out_gemm
    ushort* wql = wqh + (size_t)1536 * 512;
    ushort* woh = qhi;                          // q dead after attn
    ushort* wol = qhi + (size_t)512 * 512;

    split_w_k<<<dim3(48, 16), 256, 0, stream>>>(w_qkv, wqh, wql, 512, 1536);
    rmsnorm_k<<<TOKENS / 4, 256, 0, stream>>>(x, g, xnhi, xnlo);
    qkv_gemm_k<<<1536, 256, 0, stream>>>(
        xnhi, xnlo, wqh, wql, q_scale, k_scale,
        qhi, qlo, khi, klo, vthi, vtlo);
    attn_k<<<1024, 256, 0, stream>>>(
        qhi, qlo, khi, klo, vthi, vtlo, Ohi, Olo);
    split_w_k<<<dim3(16, 16), 256, 0, stream>>>(w_out, woh, wol, 512, 512);
    out_gemm_k<<<512, 256, 0, stream>>>(Ohi, Olo, woh, wol, out);
}